// Round 8
// baseline (380.574 us; speedup 1.0000x reference)
//
#include <hip/hip_runtime.h>
#include <hip/hip_fp16.h>

// Graph-attention sequential sweep as dataflow over the dependency DAG.
// Node i depends only on rows g[j] for j in neighbors[i], j<i, k<deg[i].
//
// R8 = R7 (verified 196us attn: fp16 gather mirror, static round-robin ids,
// 1024 blocks, separate precomp, eager online-softmax) + NON-TEMPORAL hints
// on every zero-reuse stream:
//  - out f32 stores (write-only, never read on-device)      -> nt
//  - center-row f32 loads (each row read exactly once)      -> nt
//  - precomp feats f32 loads (read exactly once)            -> nt
// Theory: R7's FETCH_SIZE=450MB vs ~160MB ideal => ~290MB of LLC-capacity
// re-fetches of the f16 gather pool, evicted by these streams. nt keeps the
// LLC holding (almost) only the 102MB f16 pool.
//
// R6 lesson encoded: do NOT raise co-residency past 16 waves/CU (LLC thrash);
// do NOT fuse precomp. Stride 4096: consecutive ids on distinct waves (R4:
// opposite is catastrophic). R5 lesson: no global atomic counter.
//
// Deadlock-freedom: all 4096 waves co-resident (4 blocks/CU x 256 CU, LDS=0,
// VGPR<=128 via __launch_bounds__(256,4)). Smallest unfinished id u is owned
// by wave u%4096; all ids < u finished -> its deps are published -> progress.
//
// Coherence (NO buffer_inv / NO buffer_wbl2):
//  - producer: out16 row written through to LLC (sc0 sc1); ej_new (combined
//    payload+ready flag, bits==0 => not ready, +0.0 nudged to denormal) via
//    relaxed agent atomic store, ordered after out16 by s_waitcnt(0).
//  - consumer: polls ej_new with relaxed agent loads (sc1, no L2 inv);
//    reads out16 rows with NORMAL cached loads — safe because each 1KB row
//    occupies exclusive cachelines, is written once, and is first read only
//    after its ej_new is seen nonzero (no stale copy can exist in any cache).

constexpr int NN   = 50000;
constexpr int D    = 512;
constexpr int K    = 32;
constexpr int D4   = D / 4;   // 128 float4 per f32 row
constexpr int DU16 = D / 2;   // 256 u32 per f16 row (512 halves)

typedef float        v4f __attribute__((ext_vector_type(4)));
typedef unsigned int v4u __attribute__((ext_vector_type(4)));

__device__ __forceinline__ void store_f4_llc(float* p, float4 v) {
    v4f vv; vv.x = v.x; vv.y = v.y; vv.z = v.z; vv.w = v.w;
    asm volatile("global_store_dwordx4 %0, %1, off sc0 sc1"
                 :: "v"(p), "v"(vv) : "memory");
}
__device__ __forceinline__ void store_u4_llc(unsigned int* p, v4u v) {
    asm volatile("global_store_dwordx4 %0, %1, off sc0 sc1"
                 :: "v"(p), "v"(v) : "memory");
}
// non-temporal (stream) accesses — compiler keeps waitcnt tracking
__device__ __forceinline__ float4 load_f4_nt(const float4* p) {
    v4f r = __builtin_nontemporal_load((const v4f*)p);
    float4 f; f.x = r.x; f.y = r.y; f.z = r.z; f.w = r.w; return f;
}
__device__ __forceinline__ void store_f4_nt(float4* p, float4 v) {
    v4f vv; vv.x = v.x; vv.y = v.y; vv.z = v.z; vv.w = v.w;
    __builtin_nontemporal_store(vv, (v4f*)p);
}
__device__ __forceinline__ unsigned int packh2(float a, float b) {
    __half2 h = __floats2half2_rn(a, b);
    return *reinterpret_cast<unsigned int*>(&h);
}
__device__ __forceinline__ float2 unpackh2(unsigned int u) {
    __half2 h = *reinterpret_cast<__half2*>(&u);
    return __half22float2(h);
}

__global__ __launch_bounds__(256) void precomp_kernel(
    const float* __restrict__ feats,
    const float* __restrict__ wq_w, const float* __restrict__ wq_b,
    const float* __restrict__ wk_w, const float* __restrict__ wk_b,
    float* __restrict__ ei, float* __restrict__ ej_orig,
    unsigned int* __restrict__ feats16)   // may be null (f32 fallback path)
{
    int gw   = (int)((blockIdx.x * blockDim.x + threadIdx.x) >> 6); // global wave id
    int lane = threadIdx.x & 63;
    if (gw >= NN) return;
    const float4* row = (const float4*)feats + (size_t)gw * D4;
    const float4* q4  = (const float4*)wq_w;
    const float4* k4  = (const float4*)wk_w;
    // lane owns elements [8*lane .. 8*lane+7]; feats is zero-reuse -> nt loads
    float4 v0 = load_f4_nt(row + 2 * lane), v1 = load_f4_nt(row + 2 * lane + 1);
    float4 q0 = q4[2 * lane],  q1 = q4[2 * lane + 1];
    float4 k0 = k4[2 * lane],  k1 = k4[2 * lane + 1];
    float dq = v0.x*q0.x + v0.y*q0.y + v0.z*q0.z + v0.w*q0.w
             + v1.x*q1.x + v1.y*q1.y + v1.z*q1.z + v1.w*q1.w;
    float dk = v0.x*k0.x + v0.y*k0.y + v0.z*k0.z + v0.w*k0.w
             + v1.x*k1.x + v1.y*k1.y + v1.z*k1.z + v1.w*k1.w;
#pragma unroll
    for (int off = 32; off > 0; off >>= 1) {
        dq += __shfl_down(dq, off, 64);
        dk += __shfl_down(dk, off, 64);
    }
    if (feats16) {
        v4u p;
        p.x = packh2(v0.x, v0.y); p.y = packh2(v0.z, v0.w);
        p.z = packh2(v1.x, v1.y); p.w = packh2(v1.z, v1.w);
        *(v4u*)(feats16 + (size_t)gw * DU16 + 4 * lane) = p;  // plain store;
        // visible to the attn kernel via stream-order kernel boundary.
    }
    if (lane == 0) {
        ei[gw]      = dq + wq_b[0];
        ej_orig[gw] = dk + wk_b[0];
    }
}

// ---------------- fp16-gather dataflow kernel (primary path) ----------------
__global__ __launch_bounds__(256, 4) void attn_dataflow_h16(
    const float* __restrict__ feats,
    const int* __restrict__ neighbors, const int* __restrict__ deg,
    const float* __restrict__ ei_arr, const float* __restrict__ ej_orig,
    const float* __restrict__ wk_w, const float* __restrict__ wk_b,
    const unsigned int* __restrict__ feats16, unsigned int* __restrict__ out16,
    int* ej_new, float* out)
{
    const int lane   = threadIdx.x & 63;
    const int gwave  = (int)((blockIdx.x * blockDim.x + threadIdx.x) >> 6);
    const int nwaves = (int)((gridDim.x * blockDim.x) >> 6);
    const float4* f4  = (const float4*)feats;
    const float4* wk4 = (const float4*)wk_w;
    const float   wkb = wk_b[0];

    for (int id = gwave; id < NN; id += nwaves) {
        const int d = deg[id];
        int nbr = 0;
        if (lane < K) nbr = neighbors[(size_t)id * K + lane];
        const bool valid = lane < d;                 // d <= 32
        const bool isdep = valid && (nbr < id);

        // center row, lane elements [8*lane .. 8*lane+7] (f32, read once -> nt)
        const float4 c0 = load_f4_nt(f4 + (size_t)id * D4 + 2 * lane);
        const float4 c1 = load_f4_nt(f4 + (size_t)id * D4 + 2 * lane + 1);
        const float eii = ei_arr[id];

        float eij = 0.f;
        if (valid && !isdep) eij = eii * ej_orig[nbr];

        // ---- eager online-softmax over ready neighbors ----
        float4 acc0 = {0.f, 0.f, 0.f, 0.f};
        float4 acc1 = {0.f, 0.f, 0.f, 0.f};
        float m = -3.0e38f, s = 0.f;

        unsigned long long pend = __ballot(valid && !isdep);
        unsigned long long wait = __ballot(isdep);

        while (pend | wait) {
            if (!pend) {
                // poll ALL remaining deps in parallel (one lane each)
                int pv = 0;
                const bool w = (wait >> lane) & 1ULL;
                if (w) pv = __hip_atomic_load(&ej_new[nbr], __ATOMIC_RELAXED,
                                              __HIP_MEMORY_SCOPE_AGENT);
                unsigned long long ready = __ballot(w && pv != 0);
                if (!ready) { __builtin_amdgcn_s_sleep(1); continue; }
                if (w && pv != 0) eij = eii * __int_as_float(pv);
                pend = ready;
                wait &= ~ready;
            }
            // take up to 8 ready neighbors; static indexing, duplicates
            // clamp to the last valid slot and get weight exp(-inf) = 0.
            int js_[8]; float ee[8]; int klast = 0;
#pragma unroll
            for (int t = 0; t < 8; ++t) {
                const bool has = (pend != 0);            // wave-uniform
                int k = has ? ((int)__ffsll(pend) - 1) : klast;
                if (has) pend &= pend - 1;
                klast = k;
                float ev = __shfl(eij, k, 64);
                ee[t] = has ? ev : -3.0e38f;
                js_[t] = __shfl(nbr, k, 64);
            }
            // issue all 8 f16-row loads (16B/lane each) before any exp/rescale
            v4u pv8[8];
#pragma unroll
            for (int t = 0; t < 8; ++t) {
                const unsigned int* sp = ((js_[t] < id) ? out16 : feats16)
                                         + (size_t)js_[t] * DU16 + 4 * lane;
                pv8[t] = *(const v4u*)sp;
            }
            float mb = m;
#pragma unroll
            for (int t = 0; t < 8; ++t) mb = fmaxf(mb, ee[t]);
            if (mb > m) {
                const float r = __expf(m - mb);   // first time: exp(-inf)=0
                acc0.x *= r; acc0.y *= r; acc0.z *= r; acc0.w *= r;
                acc1.x *= r; acc1.y *= r; acc1.z *= r; acc1.w *= r;
                s *= r; m = mb;
            }
#pragma unroll
            for (int t = 0; t < 8; ++t) {
                const float wt = __expf(ee[t] - m);      // dup: exp(-inf)=0
                s += wt;
                float2 f0 = unpackh2(pv8[t].x), f1 = unpackh2(pv8[t].y);
                float2 f2 = unpackh2(pv8[t].z), f3 = unpackh2(pv8[t].w);
                acc0.x += wt * f0.x; acc0.y += wt * f0.y;
                acc0.z += wt * f1.x; acc0.w += wt * f1.y;
                acc1.x += wt * f2.x; acc1.y += wt * f2.y;
                acc1.z += wt * f3.x; acc1.w += wt * f3.y;
            }
        }

        const float inv_s = (s > 0.f) ? (1.0f / s) : 0.f;  // d==0 -> acc==0
        float4 g0 = {c0.x + acc0.x * inv_s, c0.y + acc0.y * inv_s,
                     c0.z + acc0.z * inv_s, c0.w + acc0.w * inv_s};
        float4 g1 = {c1.x + acc1.x * inv_s, c1.y + acc1.y * inv_s,
                     c1.z + acc1.z * inv_s, c1.w + acc1.w * inv_s};

        // f32 result row: nobody reads it on-device -> non-temporal stores
        float4* orow4 = (float4*)out + (size_t)id * D4;
        store_f4_nt(orow4 + 2 * lane,     g0);
        store_f4_nt(orow4 + 2 * lane + 1, g1);

        // f16 mirror row: the gather payload, write-through + flag-ordered
        v4u pg;
        pg.x = packh2(g0.x, g0.y); pg.y = packh2(g0.z, g0.w);
        pg.z = packh2(g1.x, g1.y); pg.w = packh2(g1.z, g1.w);
        store_u4_llc(out16 + (size_t)id * DU16 + 4 * lane, pg);

        // ej_new[id] = g . wk + bk  (computed while stores are in flight)
        float4 w0 = wk4[2 * lane], w1 = wk4[2 * lane + 1];
        float pd = g0.x * w0.x + g0.y * w0.y + g0.z * w0.z + g0.w * w0.w
                 + g1.x * w1.x + g1.y * w1.y + g1.z * w1.z + g1.w * w1.w;
#pragma unroll
        for (int off = 32; off > 0; off >>= 1)
            pd += __shfl_xor(pd, off, 64);

        int bits = __float_as_int(pd + wkb);
        if (bits == 0) bits = 1;   // avoid the not-ready sentinel

        // order the out16 payload (at LLC) before the combined flag+payload
        __builtin_amdgcn_s_waitcnt(0);
        if (lane == 0)
            __hip_atomic_store(&ej_new[id], bits,
                               __ATOMIC_RELAXED, __HIP_MEMORY_SCOPE_AGENT);
    }
}

// ---------------- f32 fallback (verbatim R5 kernel, 260us verified) ---------
__global__ __launch_bounds__(256, 4) void attn_dataflow_f32(
    const float* __restrict__ feats,
    const int* __restrict__ neighbors, const int* __restrict__ deg,
    const float* __restrict__ ei_arr, const float* __restrict__ ej_orig,
    const float* __restrict__ wk_w, const float* __restrict__ wk_b,
    int* ej_new, float* out)
{
    const int lane   = threadIdx.x & 63;
    const int gwave  = (int)((blockIdx.x * blockDim.x + threadIdx.x) >> 6);
    const int nwaves = (int)((gridDim.x * blockDim.x) >> 6);
    const float4* f4  = (const float4*)feats;
    const float4* o4r = (const float4*)out;
    const float4* wk4 = (const float4*)wk_w;
    const float   wkb = wk_b[0];

    for (int id = gwave; id < NN; id += nwaves) {
        const int d = deg[id];
        int nbr = 0;
        if (lane < K) nbr = neighbors[(size_t)id * K + lane];
        const bool valid = lane < d;
        const bool isdep = valid && (nbr < id);

        const float4 c0 = f4[(size_t)id * D4 + lane];
        const float4 c1 = f4[(size_t)id * D4 + lane + 64];
        const float eii = ei_arr[id];

        float eij = 0.f;
        if (valid && !isdep) eij = eii * ej_orig[nbr];

        float4 acc0 = {0.f, 0.f, 0.f, 0.f};
        float4 acc1 = {0.f, 0.f, 0.f, 0.f};
        float m = -3.0e38f, s = 0.f;

        unsigned long long pend = __ballot(valid && !isdep);
        unsigned long long wait = __ballot(isdep);

        while (pend | wait) {
            if (!pend) {
                int pv = 0;
                const bool w = (wait >> lane) & 1ULL;
                if (w) pv = __hip_atomic_load(&ej_new[nbr], __ATOMIC_RELAXED,
                                              __HIP_MEMORY_SCOPE_AGENT);
                unsigned long long ready = __ballot(w && pv != 0);
                if (!ready) { __builtin_amdgcn_s_sleep(1); continue; }
                if (w && pv != 0) eij = eii * __int_as_float(pv);
                pend = ready;
                wait &= ~ready;
            }
            int cnt = 0;
            int   js[4]; float ee[4];
#pragma unroll
            for (int t = 0; t < 4; ++t) {
                if (pend) {
                    int k = (int)__ffsll(pend) - 1;
                    pend &= pend - 1;
                    ee[cnt] = __shfl(eij, k, 64);
                    js[cnt] = __shfl(nbr, k, 64);
                    ++cnt;
                }
            }
            float4 v0[4], v1[4];
#pragma unroll
            for (int t = 0; t < 4; ++t) {
                if (t < cnt) {
                    const float4* sp = (js[t] < id) ? (o4r + (size_t)js[t] * D4)
                                                    : (f4  + (size_t)js[t] * D4);
                    v0[t] = sp[lane];
                    v1[t] = sp[lane + 64];
                }
            }
            float mb = m;
#pragma unroll
            for (int t = 0; t < 4; ++t) if (t < cnt) mb = fmaxf(mb, ee[t]);
            if (mb > m) {
                const float r = __expf(m - mb);
                acc0.x *= r; acc0.y *= r; acc0.z *= r; acc0.w *= r;
                acc1.x *= r; acc1.y *= r; acc1.z *= r; acc1.w *= r;
                s *= r; m = mb;
            }
#pragma unroll
            for (int t = 0; t < 4; ++t) {
                if (t < cnt) {
                    const float wt = __expf(ee[t] - m);
                    s += wt;
                    acc0.x += wt * v0[t].x; acc0.y += wt * v0[t].y;
                    acc0.z += wt * v0[t].z; acc0.w += wt * v0[t].w;
                    acc1.x += wt * v1[t].x; acc1.y += wt * v1[t].y;
                    acc1.z += wt * v1[t].z; acc1.w += wt * v1[t].w;
                }
            }
        }

        const float inv_s = (s > 0.f) ? (1.0f / s) : 0.f;
        float4 g0 = {c0.x + acc0.x * inv_s, c0.y + acc0.y * inv_s,
                     c0.z + acc0.z * inv_s, c0.w + acc0.w * inv_s};
        float4 g1 = {c1.x + acc1.x * inv_s, c1.y + acc1.y * inv_s,
                     c1.z + acc1.z * inv_s, c1.w + acc1.w * inv_s};
        float* orow = out + (size_t)id * D;
        store_f4_llc(orow + 4 * lane,        g0);
        store_f4_llc(orow + 4 * (lane + 64), g1);

        float4 w0 = wk4[lane], w1 = wk4[lane + 64];
        float pd = g0.x * w0.x + g0.y * w0.y + g0.z * w0.z + g0.w * w0.w
                 + g1.x * w1.x + g1.y * w1.y + g1.z * w1.z + g1.w * w1.w;
#pragma unroll
        for (int off = 32; off > 0; off >>= 1)
            pd += __shfl_xor(pd, off, 64);

        int bits = __float_as_int(pd + wkb);
        if (bits == 0) bits = 1;

        __builtin_amdgcn_s_waitcnt(0);
        if (lane == 0)
            __hip_atomic_store(&ej_new[id], bits,
                               __ATOMIC_RELAXED, __HIP_MEMORY_SCOPE_AGENT);
    }
}

extern "C" void kernel_launch(void* const* d_in, const int* in_sizes, int n_in,
                              void* d_out, int out_size, void* d_ws, size_t ws_size,
                              hipStream_t stream)
{
    const float* feats     = (const float*)d_in[0];
    const float* wq_w      = (const float*)d_in[1];
    const float* wq_b      = (const float*)d_in[2];
    const float* wk_w      = (const float*)d_in[3];
    const float* wk_b      = (const float*)d_in[4];
    const int*   neighbors = (const int*)d_in[5];
    const int*   deg       = (const int*)d_in[6];
    float*       out       = (float*)d_out;

    // ws: [ej_new: NN i][pad 64][ei: NN f][ej_orig: NN f] | align1024 |
    //     [feats16: NN*1KB][out16: NN*1KB]   (f16 mirror, if ws_size allows)
    char*  ws      = (char*)d_ws;
    int*   ej_new  = (int*)ws;
    float* ei      = (float*)(ej_new + NN + 64);
    float* ej_orig = ei + NN;
    size_t scal_end = (size_t)((char*)(ej_orig + NN) - ws);
    size_t f16_off  = (scal_end + 1023) & ~(size_t)1023;
    size_t f16_need = 2ull * NN * DU16 * sizeof(unsigned int);  // 102.4 MB
    const bool use16 = (ws_size >= f16_off + f16_need);
    unsigned int* feats16 = (unsigned int*)(ws + f16_off);
    unsigned int* out16   = feats16 + (size_t)NN * DU16;

    (void)hipMemsetAsync(d_ws, 0, (size_t)NN * sizeof(int), stream);  // ej_new=0

    dim3 pb(256), pg((NN + 3) / 4);
    precomp_kernel<<<pg, pb, 0, stream>>>(feats, wq_w, wq_b, wk_w, wk_b,
                                          ei, ej_orig, use16 ? feats16 : nullptr);

    if (use16) {
        attn_dataflow_h16<<<dim3(1024), dim3(256), 0, stream>>>(
            feats, neighbors, deg, ei, ej_orig, wk_w, wk_b,
            feats16, out16, ej_new, out);
    } else {
        attn_dataflow_f32<<<dim3(1024), dim3(256), 0, stream>>>(
            feats, neighbors, deg, ei, ej_orig, wk_w, wk_b, ej_new, out);
    }
}

// Round 9
// 374.848 us; speedup vs baseline: 1.0153x; 1.0153x over previous
//
#include <hip/hip_runtime.h>
#include <hip/hip_fp16.h>

// Graph-attention sequential sweep as dataflow over the dependency DAG.
// Node i depends only on rows g[j] for j in neighbors[i], j<i, k<deg[i].
//
// R9 = R7 (verified 196us attn) + chain-step shortening:
//  (1) SCALAR ej_new: ej_new[i] = g.wk+wkb = ej_orig[i] + (1/s)*sum(wt*ej_t)
//      - wkb  — all wave-uniform scalars already in registers (ej_t are the
//      polled neighbor values). Deletes the 16-FMA dot + 6-shfl reduce from
//      every node and every chain step (~250-400cy).
//  (2) out f32 row store moved AFTER the ej_new publish (no device consumer;
//      host sees it via kernel-end drain). The pre-publish s_waitcnt(0) now
//      drains only the out16 LLC write-through. R8's regression proved the
//      f32-store drain was sitting on the critical chain.
// R8 lesson: nt hints do NOT reduce LLC re-fetches (memory-side cache,
// everything allocates); nt stores BEFORE the publish drain cost +12us.
//
// R6 lesson: do NOT raise co-residency past 16 waves/CU; do NOT fuse
// precomp. R4/R5 lessons: consecutive ids on distinct waves; no global
// atomic counter.
//
// Deadlock-freedom: all 4096 waves co-resident (4 blocks/CU x 256 CU, LDS=0,
// VGPR<=128 via __launch_bounds__(256,4)). Smallest unfinished id u is owned
// by wave u%4096; all ids < u finished -> its deps are published -> progress.
//
// Coherence (NO buffer_inv / NO buffer_wbl2):
//  - producer: out16 row written through to LLC (sc0 sc1); ej_new (combined
//    payload+ready flag, bits==0 => not ready, +0.0 nudged to denormal) via
//    relaxed agent atomic store, ordered after out16 by s_waitcnt(0).
//  - consumer: polls ej_new with relaxed agent loads (sc1, no L2 inv);
//    reads out16 rows with NORMAL cached loads — safe because each 1KB row
//    occupies exclusive cachelines, is written once, and is first read only
//    after its ej_new is seen nonzero (no stale copy can exist in any cache).

constexpr int NN   = 50000;
constexpr int D    = 512;
constexpr int K    = 32;
constexpr int D4   = D / 4;   // 128 float4 per f32 row
constexpr int DU16 = D / 2;   // 256 u32 per f16 row (512 halves)

typedef float        v4f __attribute__((ext_vector_type(4)));
typedef unsigned int v4u __attribute__((ext_vector_type(4)));

__device__ __forceinline__ void store_u4_llc(unsigned int* p, v4u v) {
    asm volatile("global_store_dwordx4 %0, %1, off sc0 sc1"
                 :: "v"(p), "v"(v) : "memory");
}
__device__ __forceinline__ void store_f4_llc(float* p, float4 v) {
    v4f vv; vv.x = v.x; vv.y = v.y; vv.z = v.z; vv.w = v.w;
    asm volatile("global_store_dwordx4 %0, %1, off sc0 sc1"
                 :: "v"(p), "v"(vv) : "memory");
}
// non-temporal (stream) accesses — compiler keeps waitcnt tracking
__device__ __forceinline__ float4 load_f4_nt(const float4* p) {
    v4f r = __builtin_nontemporal_load((const v4f*)p);
    float4 f; f.x = r.x; f.y = r.y; f.z = r.z; f.w = r.w; return f;
}
__device__ __forceinline__ void store_f4_nt(float4* p, float4 v) {
    v4f vv; vv.x = v.x; vv.y = v.y; vv.z = v.z; vv.w = v.w;
    __builtin_nontemporal_store(vv, (v4f*)p);
}
__device__ __forceinline__ unsigned int packh2(float a, float b) {
    __half2 h = __floats2half2_rn(a, b);
    return *reinterpret_cast<unsigned int*>(&h);
}
__device__ __forceinline__ float2 unpackh2(unsigned int u) {
    __half2 h = *reinterpret_cast<__half2*>(&u);
    return __half22float2(h);
}

__global__ __launch_bounds__(256) void precomp_kernel(
    const float* __restrict__ feats,
    const float* __restrict__ wq_w, const float* __restrict__ wq_b,
    const float* __restrict__ wk_w, const float* __restrict__ wk_b,
    float* __restrict__ ei, float* __restrict__ ej_orig,
    unsigned int* __restrict__ feats16)   // may be null (f32 fallback path)
{
    int gw   = (int)((blockIdx.x * blockDim.x + threadIdx.x) >> 6); // global wave id
    int lane = threadIdx.x & 63;
    if (gw >= NN) return;
    const float4* row = (const float4*)feats + (size_t)gw * D4;
    const float4* q4  = (const float4*)wq_w;
    const float4* k4  = (const float4*)wk_w;
    // lane owns elements [8*lane .. 8*lane+7]; feats is zero-reuse -> nt loads
    float4 v0 = load_f4_nt(row + 2 * lane), v1 = load_f4_nt(row + 2 * lane + 1);
    float4 q0 = q4[2 * lane],  q1 = q4[2 * lane + 1];
    float4 k0 = k4[2 * lane],  k1 = k4[2 * lane + 1];
    float dq = v0.x*q0.x + v0.y*q0.y + v0.z*q0.z + v0.w*q0.w
             + v1.x*q1.x + v1.y*q1.y + v1.z*q1.z + v1.w*q1.w;
    float dk = v0.x*k0.x + v0.y*k0.y + v0.z*k0.z + v0.w*k0.w
             + v1.x*k1.x + v1.y*k1.y + v1.z*k1.z + v1.w*k1.w;
#pragma unroll
    for (int off = 32; off > 0; off >>= 1) {
        dq += __shfl_down(dq, off, 64);
        dk += __shfl_down(dk, off, 64);
    }
    if (feats16) {
        v4u p;
        p.x = packh2(v0.x, v0.y); p.y = packh2(v0.z, v0.w);
        p.z = packh2(v1.x, v1.y); p.w = packh2(v1.z, v1.w);
        *(v4u*)(feats16 + (size_t)gw * DU16 + 4 * lane) = p;  // plain store;
        // visible to the attn kernel via stream-order kernel boundary.
    }
    if (lane == 0) {
        ei[gw]      = dq + wq_b[0];
        ej_orig[gw] = dk + wk_b[0];
    }
}

// ---------------- fp16-gather dataflow kernel (primary path) ----------------
__global__ __launch_bounds__(256, 4) void attn_dataflow_h16(
    const float* __restrict__ feats,
    const int* __restrict__ neighbors, const int* __restrict__ deg,
    const float* __restrict__ ei_arr, const float* __restrict__ ej_orig,
    const float* __restrict__ wk_b,
    const unsigned int* __restrict__ feats16, unsigned int* __restrict__ out16,
    int* ej_new, float* out)
{
    const int lane   = threadIdx.x & 63;
    const int gwave  = (int)((blockIdx.x * blockDim.x + threadIdx.x) >> 6);
    const int nwaves = (int)((gridDim.x * blockDim.x) >> 6);
    const float4* f4  = (const float4*)feats;
    const float   wkb = wk_b[0];

    for (int id = gwave; id < NN; id += nwaves) {
        const int d = deg[id];
        int nbr = 0;
        if (lane < K) nbr = neighbors[(size_t)id * K + lane];
        const bool valid = lane < d;                 // d <= 32
        const bool isdep = valid && (nbr < id);

        // center row, lane elements [8*lane .. 8*lane+7] (f32, read once -> nt)
        const float4 c0 = load_f4_nt(f4 + (size_t)id * D4 + 2 * lane);
        const float4 c1 = load_f4_nt(f4 + (size_t)id * D4 + 2 * lane + 1);
        const float eii  = ei_arr[id];
        const float ejoc = ej_orig[id];   // own w_k(feats[id]) — exact value

        float ejraw = 0.f, eij = 0.f;
        if (valid && !isdep) { ejraw = ej_orig[nbr]; eij = eii * ejraw; }

        // ---- eager online-softmax over ready neighbors ----
        float4 acc0 = {0.f, 0.f, 0.f, 0.f};
        float4 acc1 = {0.f, 0.f, 0.f, 0.f};
        float m = -3.0e38f, s = 0.f, se = 0.f;   // se = sum(wt * ej_t)

        unsigned long long pend = __ballot(valid && !isdep);
        unsigned long long wait = __ballot(isdep);

        while (pend | wait) {
            if (!pend) {
                // poll ALL remaining deps in parallel (one lane each)
                int pv = 0;
                const bool w = (wait >> lane) & 1ULL;
                if (w) pv = __hip_atomic_load(&ej_new[nbr], __ATOMIC_RELAXED,
                                              __HIP_MEMORY_SCOPE_AGENT);
                unsigned long long ready = __ballot(w && pv != 0);
                if (!ready) { __builtin_amdgcn_s_sleep(1); continue; }
                if (w && pv != 0) { ejraw = __int_as_float(pv); eij = eii * ejraw; }
                pend = ready;
                wait &= ~ready;
            }
            // take up to 8 ready neighbors; static indexing, duplicates
            // clamp to the last valid slot and get weight exp(-inf) = 0.
            int js_[8]; float ee[8], ev2[8]; int klast = 0;
#pragma unroll
            for (int t = 0; t < 8; ++t) {
                const bool has = (pend != 0);            // wave-uniform
                int k = has ? ((int)__ffsll(pend) - 1) : klast;
                if (has) pend &= pend - 1;
                klast = k;
                float ev = __shfl(eij, k, 64);
                ee[t]  = has ? ev : -3.0e38f;
                ev2[t] = __shfl(ejraw, k, 64);
                js_[t] = __shfl(nbr, k, 64);
            }
            // issue all 8 f16-row loads (16B/lane each) before any exp/rescale
            v4u pv8[8];
#pragma unroll
            for (int t = 0; t < 8; ++t) {
                const unsigned int* sp = ((js_[t] < id) ? out16 : feats16)
                                         + (size_t)js_[t] * DU16 + 4 * lane;
                pv8[t] = *(const v4u*)sp;
            }
            float mb = m;
#pragma unroll
            for (int t = 0; t < 8; ++t) mb = fmaxf(mb, ee[t]);
            if (mb > m) {
                const float r = __expf(m - mb);   // first time: exp(-inf)=0
                acc0.x *= r; acc0.y *= r; acc0.z *= r; acc0.w *= r;
                acc1.x *= r; acc1.y *= r; acc1.z *= r; acc1.w *= r;
                s *= r; se *= r; m = mb;
            }
#pragma unroll
            for (int t = 0; t < 8; ++t) {
                const float wt = __expf(ee[t] - m);      // dup: exp(-inf)=0
                s  += wt;
                se += wt * ev2[t];
                float2 f0 = unpackh2(pv8[t].x), f1 = unpackh2(pv8[t].y);
                float2 f2 = unpackh2(pv8[t].z), f3 = unpackh2(pv8[t].w);
                acc0.x += wt * f0.x; acc0.y += wt * f0.y;
                acc0.z += wt * f1.x; acc0.w += wt * f1.y;
                acc1.x += wt * f2.x; acc1.y += wt * f2.y;
                acc1.z += wt * f3.x; acc1.w += wt * f3.y;
            }
        }

        const float inv_s = (s > 0.f) ? (1.0f / s) : 0.f;  // d==0 -> acc==0
        float4 g0 = {c0.x + acc0.x * inv_s, c0.y + acc0.y * inv_s,
                     c0.z + acc0.z * inv_s, c0.w + acc0.w * inv_s};
        float4 g1 = {c1.x + acc1.x * inv_s, c1.y + acc1.y * inv_s,
                     c1.z + acc1.z * inv_s, c1.w + acc1.w * inv_s};

        // f16 mirror row FIRST: the gather payload, write-through + flag-ordered
        v4u pg;
        pg.x = packh2(g0.x, g0.y); pg.y = packh2(g0.z, g0.w);
        pg.z = packh2(g1.x, g1.y); pg.w = packh2(g1.z, g1.w);
        store_u4_llc(out16 + (size_t)id * DU16 + 4 * lane, pg);

        // scalar ej_new (no dot, no reduce): g.wk+wkb = ejoc + se/s - wkb
        const float ejn = ejoc + ((s > 0.f) ? (se * inv_s - wkb) : 0.f);
        int bits = __float_as_int(ejn);
        if (bits == 0) bits = 1;   // avoid the not-ready sentinel

        // order the out16 payload (at LLC) before the combined flag+payload
        __builtin_amdgcn_s_waitcnt(0);
        if (lane == 0)
            __hip_atomic_store(&ej_new[id], bits,
                               __ATOMIC_RELAXED, __HIP_MEMORY_SCOPE_AGENT);

        // f32 result row AFTER publish: no device consumer, off the chain
        float4* orow4 = (float4*)out + (size_t)id * D4;
        store_f4_nt(orow4 + 2 * lane,     g0);
        store_f4_nt(orow4 + 2 * lane + 1, g1);
    }
}

// ---------------- f32 fallback (verbatim R5 kernel, 260us verified) ---------
__global__ __launch_bounds__(256, 4) void attn_dataflow_f32(
    const float* __restrict__ feats,
    const int* __restrict__ neighbors, const int* __restrict__ deg,
    const float* __restrict__ ei_arr, const float* __restrict__ ej_orig,
    const float* __restrict__ wk_w, const float* __restrict__ wk_b,
    int* ej_new, float* out)
{
    const int lane   = threadIdx.x & 63;
    const int gwave  = (int)((blockIdx.x * blockDim.x + threadIdx.x) >> 6);
    const int nwaves = (int)((gridDim.x * blockDim.x) >> 6);
    const float4* f4  = (const float4*)feats;
    const float4* o4r = (const float4*)out;
    const float4* wk4 = (const float4*)wk_w;
    const float   wkb = wk_b[0];

    for (int id = gwave; id < NN; id += nwaves) {
        const int d = deg[id];
        int nbr = 0;
        if (lane < K) nbr = neighbors[(size_t)id * K + lane];
        const bool valid = lane < d;
        const bool isdep = valid && (nbr < id);

        const float4 c0 = f4[(size_t)id * D4 + lane];
        const float4 c1 = f4[(size_t)id * D4 + lane + 64];
        const float eii = ei_arr[id];

        float eij = 0.f;
        if (valid && !isdep) eij = eii * ej_orig[nbr];

        float4 acc0 = {0.f, 0.f, 0.f, 0.f};
        float4 acc1 = {0.f, 0.f, 0.f, 0.f};
        float m = -3.0e38f, s = 0.f;

        unsigned long long pend = __ballot(valid && !isdep);
        unsigned long long wait = __ballot(isdep);

        while (pend | wait) {
            if (!pend) {
                int pv = 0;
                const bool w = (wait >> lane) & 1ULL;
                if (w) pv = __hip_atomic_load(&ej_new[nbr], __ATOMIC_RELAXED,
                                              __HIP_MEMORY_SCOPE_AGENT);
                unsigned long long ready = __ballot(w && pv != 0);
                if (!ready) { __builtin_amdgcn_s_sleep(1); continue; }
                if (w && pv != 0) eij = eii * __int_as_float(pv);
                pend = ready;
                wait &= ~ready;
            }
            int cnt = 0;
            int   js[4]; float ee[4];
#pragma unroll
            for (int t = 0; t < 4; ++t) {
                if (pend) {
                    int k = (int)__ffsll(pend) - 1;
                    pend &= pend - 1;
                    ee[cnt] = __shfl(eij, k, 64);
                    js[cnt] = __shfl(nbr, k, 64);
                    ++cnt;
                }
            }
            float4 v0[4], v1[4];
#pragma unroll
            for (int t = 0; t < 4; ++t) {
                if (t < cnt) {
                    const float4* sp = (js[t] < id) ? (o4r + (size_t)js[t] * D4)
                                                    : (f4  + (size_t)js[t] * D4);
                    v0[t] = sp[lane];
                    v1[t] = sp[lane + 64];
                }
            }
            float mb = m;
#pragma unroll
            for (int t = 0; t < 4; ++t) if (t < cnt) mb = fmaxf(mb, ee[t]);
            if (mb > m) {
                const float r = __expf(m - mb);
                acc0.x *= r; acc0.y *= r; acc0.z *= r; acc0.w *= r;
                acc1.x *= r; acc1.y *= r; acc1.z *= r; acc1.w *= r;
                s *= r; m = mb;
            }
#pragma unroll
            for (int t = 0; t < 4; ++t) {
                if (t < cnt) {
                    const float wt = __expf(ee[t] - m);
                    s += wt;
                    acc0.x += wt * v0[t].x; acc0.y += wt * v0[t].y;
                    acc0.z += wt * v0[t].z; acc0.w += wt * v0[t].w;
                    acc1.x += wt * v1[t].x; acc1.y += wt * v1[t].y;
                    acc1.z += wt * v1[t].z; acc1.w += wt * v1[t].w;
                }
            }
        }

        const float inv_s = (s > 0.f) ? (1.0f / s) : 0.f;
        float4 g0 = {c0.x + acc0.x * inv_s, c0.y + acc0.y * inv_s,
                     c0.z + acc0.z * inv_s, c0.w + acc0.w * inv_s};
        float4 g1 = {c1.x + acc1.x * inv_s, c1.y + acc1.y * inv_s,
                     c1.z + acc1.z * inv_s, c1.w + acc1.w * inv_s};
        float* orow = out + (size_t)id * D;
        store_f4_llc(orow + 4 * lane,        g0);
        store_f4_llc(orow + 4 * (lane + 64), g1);

        float4 w0 = wk4[lane], w1 = wk4[lane + 64];
        float pd = g0.x * w0.x + g0.y * w0.y + g0.z * w0.z + g0.w * w0.w
                 + g1.x * w1.x + g1.y * w1.y + g1.z * w1.z + g1.w * w1.w;
#pragma unroll
        for (int off = 32; off > 0; off >>= 1)
            pd += __shfl_xor(pd, off, 64);

        int bits = __float_as_int(pd + wkb);
        if (bits == 0) bits = 1;

        __builtin_amdgcn_s_waitcnt(0);
        if (lane == 0)
            __hip_atomic_store(&ej_new[id], bits,
                               __ATOMIC_RELAXED, __HIP_MEMORY_SCOPE_AGENT);
    }
}

extern "C" void kernel_launch(void* const* d_in, const int* in_sizes, int n_in,
                              void* d_out, int out_size, void* d_ws, size_t ws_size,
                              hipStream_t stream)
{
    const float* feats     = (const float*)d_in[0];
    const float* wq_w      = (const float*)d_in[1];
    const float* wq_b      = (const float*)d_in[2];
    const float* wk_w      = (const float*)d_in[3];
    const float* wk_b      = (const float*)d_in[4];
    const int*   neighbors = (const int*)d_in[5];
    const int*   deg       = (const int*)d_in[6];
    float*       out       = (float*)d_out;

    // ws: [ej_new: NN i][pad 64][ei: NN f][ej_orig: NN f] | align1024 |
    //     [feats16: NN*1KB][out16: NN*1KB]   (f16 mirror, if ws_size allows)
    char*  ws      = (char*)d_ws;
    int*   ej_new  = (int*)ws;
    float* ei      = (float*)(ej_new + NN + 64);
    float* ej_orig = ei + NN;
    size_t scal_end = (size_t)((char*)(ej_orig + NN) - ws);
    size_t f16_off  = (scal_end + 1023) & ~(size_t)1023;
    size_t f16_need = 2ull * NN * DU16 * sizeof(unsigned int);  // 102.4 MB
    const bool use16 = (ws_size >= f16_off + f16_need);
    unsigned int* feats16 = (unsigned int*)(ws + f16_off);
    unsigned int* out16   = feats16 + (size_t)NN * DU16;

    (void)hipMemsetAsync(d_ws, 0, (size_t)NN * sizeof(int), stream);  // ej_new=0

    dim3 pb(256), pg((NN + 3) / 4);
    precomp_kernel<<<pg, pb, 0, stream>>>(feats, wq_w, wq_b, wk_w, wk_b,
                                          ei, ej_orig, use16 ? feats16 : nullptr);

    if (use16) {
        attn_dataflow_h16<<<dim3(1024), dim3(256), 0, stream>>>(
            feats, neighbors, deg, ei, ej_orig, wk_b,
            feats16, out16, ej_new, out);
    } else {
        attn_dataflow_f32<<<dim3(1024), dim3(256), 0, stream>>>(
            feats, neighbors, deg, ei, ej_orig, wk_w, wk_b, ej_new, out);
    }
}

// Round 10
// 372.268 us; speedup vs baseline: 1.0223x; 1.0069x over previous
//
#include <hip/hip_runtime.h>
#include <hip/hip_fp16.h>

// Graph-attention sequential sweep as dataflow over the dependency DAG.
// Node i depends only on rows g[j] for j in neighbors[i], j<i, k<deg[i].
//
// R10 — TWO DECOUPLED DEPENDENCY CHAINS (and full nt revert to R7 regime):
//  KEY FACT: ej_new[i] = g.wk+wkb = ej_orig[i] + se/s - wkb where
//  se = sum(wt*ej_t), s = sum(wt) — scalars only. The scalar chain does not
//  need the 1KB rows at all.
//  Phase A (scalar): poll dep ej scalars -> exact 2-pass softmax (all eij
//    known up front) -> publish ej_new[id] IMMEDIATELY, no drain (no payload
//    attached; rows have their own flag). Scalar chain step ~0.3us.
//  Phase B (rows): weights final (no online rescale); eager-gather ready
//    rows (deps poll row_flag); out16 write-through (sc0 sc1) -> s_waitcnt(0)
//    -> row_flag[id]=1 -> plain cached f32 out store (off-chain).
//  All nt hints reverted: R8/R9 proved nt loads/stores cost ~12us (LLC is
//  memory-side, everything allocates; nt just degrades the access).
//
// Lessons encoded: R4 consecutive ids must land on distinct waves; R5 no
// global atomic counter; R6 do not exceed 16 waves/CU (LLC thrash), do not
// fuse precomp; R7 f16 gather mirror (halves gather bytes); R8 no nt.
//
// Deadlock-freedom: all 4096 waves co-resident (4 blocks/CU x 256 CU, LDS=0,
// VGPR<=128 via __launch_bounds__(256,4)). Induction on each sweep
// separately: smallest id with unpublished SCALAR — its owner wave's earlier
// own-ids have smaller ids (scalars published, rows progress per the row
// induction), and its scalar deps (<id) are published -> progress. Smallest
// id with unset ROW flag — its row deps (<id) are all set -> progress.
//
// Coherence (NO buffer_inv / NO buffer_wbl2):
//  - ej_new: scalar-only payload+flag word (bits==0 => not ready; +0.0
//    nudged to denormal), relaxed agent atomic store/load. No ordering
//    requirements.
//  - out16 rows: write-through to LLC (sc0 sc1); row_flag set only after
//    s_waitcnt(0) drains the row; consumers read rows with NORMAL cached
//    loads, first touch only after row_flag seen -> no stale copies.

constexpr int NN   = 50000;
constexpr int D    = 512;
constexpr int K    = 32;
constexpr int D4   = D / 4;   // 128 float4 per f32 row
constexpr int DU16 = D / 2;   // 256 u32 per f16 row (512 halves)

typedef float        v4f __attribute__((ext_vector_type(4)));
typedef unsigned int v4u __attribute__((ext_vector_type(4)));

__device__ __forceinline__ void store_u4_llc(unsigned int* p, v4u v) {
    asm volatile("global_store_dwordx4 %0, %1, off sc0 sc1"
                 :: "v"(p), "v"(v) : "memory");
}
__device__ __forceinline__ void store_f4_llc(float* p, float4 v) {
    v4f vv; vv.x = v.x; vv.y = v.y; vv.z = v.z; vv.w = v.w;
    asm volatile("global_store_dwordx4 %0, %1, off sc0 sc1"
                 :: "v"(p), "v"(vv) : "memory");
}
__device__ __forceinline__ unsigned int packh2(float a, float b) {
    __half2 h = __floats2half2_rn(a, b);
    return *reinterpret_cast<unsigned int*>(&h);
}
__device__ __forceinline__ float2 unpackh2(unsigned int u) {
    __half2 h = *reinterpret_cast<__half2*>(&u);
    return __half22float2(h);
}

__global__ __launch_bounds__(256) void precomp_kernel(
    const float* __restrict__ feats,
    const float* __restrict__ wq_w, const float* __restrict__ wq_b,
    const float* __restrict__ wk_w, const float* __restrict__ wk_b,
    float* __restrict__ ei, float* __restrict__ ej_orig,
    unsigned int* __restrict__ feats16)   // may be null (f32 fallback path)
{
    int gw   = (int)((blockIdx.x * blockDim.x + threadIdx.x) >> 6); // global wave id
    int lane = threadIdx.x & 63;
    if (gw >= NN) return;
    const float4* row = (const float4*)feats + (size_t)gw * D4;
    const float4* q4  = (const float4*)wq_w;
    const float4* k4  = (const float4*)wk_w;
    // lane owns elements [8*lane .. 8*lane+7]
    float4 v0 = row[2 * lane], v1 = row[2 * lane + 1];
    float4 q0 = q4[2 * lane],  q1 = q4[2 * lane + 1];
    float4 k0 = k4[2 * lane],  k1 = k4[2 * lane + 1];
    float dq = v0.x*q0.x + v0.y*q0.y + v0.z*q0.z + v0.w*q0.w
             + v1.x*q1.x + v1.y*q1.y + v1.z*q1.z + v1.w*q1.w;
    float dk = v0.x*k0.x + v0.y*k0.y + v0.z*k0.z + v0.w*k0.w
             + v1.x*k1.x + v1.y*k1.y + v1.z*k1.z + v1.w*k1.w;
#pragma unroll
    for (int off = 32; off > 0; off >>= 1) {
        dq += __shfl_down(dq, off, 64);
        dk += __shfl_down(dk, off, 64);
    }
    if (feats16) {
        v4u p;
        p.x = packh2(v0.x, v0.y); p.y = packh2(v0.z, v0.w);
        p.z = packh2(v1.x, v1.y); p.w = packh2(v1.z, v1.w);
        *(v4u*)(feats16 + (size_t)gw * DU16 + 4 * lane) = p;  // plain store;
        // visible to the attn kernel via stream-order kernel boundary.
    }
    if (lane == 0) {
        ei[gw]      = dq + wq_b[0];
        ej_orig[gw] = dk + wk_b[0];
    }
}

// ---------------- fp16-gather dataflow kernel (primary path) ----------------
__global__ __launch_bounds__(256, 4) void attn_dataflow_h16(
    const float* __restrict__ feats,
    const int* __restrict__ neighbors, const int* __restrict__ deg,
    const float* __restrict__ ei_arr, const float* __restrict__ ej_orig,
    const float* __restrict__ wk_b,
    const unsigned int* __restrict__ feats16, unsigned int* __restrict__ out16,
    int* ej_new, int* row_flag, float* out)
{
    const int lane   = threadIdx.x & 63;
    const int gwave  = (int)((blockIdx.x * blockDim.x + threadIdx.x) >> 6);
    const int nwaves = (int)((gridDim.x * blockDim.x) >> 6);
    const float4* f4  = (const float4*)feats;
    const float   wkb = wk_b[0];

    for (int id = gwave; id < NN; id += nwaves) {
        const int d = deg[id];
        int nbr = 0;
        if (lane < K) nbr = neighbors[(size_t)id * K + lane];
        const bool valid = lane < d;                 // d <= 32
        const bool isdep = valid && (nbr < id);

        // center row, lane elements [8*lane .. 8*lane+7] (plain cached)
        const float4 c0 = f4[(size_t)id * D4 + 2 * lane];
        const float4 c1 = f4[(size_t)id * D4 + 2 * lane + 1];
        const float eii  = ei_arr[id];
        const float ejoc = ej_orig[id];   // own w_k(feats[id]) — exact

        float ejraw = 0.f, eij = -3.0e38f;
        if (valid && !isdep) { ejraw = ej_orig[nbr]; eij = eii * ejraw; }

        // ---------------- phase A: scalar chain ----------------
        unsigned long long wait = __ballot(isdep);
        while (wait) {
            int pv = 0;
            const bool w = (wait >> lane) & 1ULL;
            if (w) pv = __hip_atomic_load(&ej_new[nbr], __ATOMIC_RELAXED,
                                          __HIP_MEMORY_SCOPE_AGENT);
            unsigned long long ready = __ballot(w && pv != 0);
            if (w && pv != 0) { ejraw = __int_as_float(pv); eij = eii * ejraw; }
            wait &= ~ready;
            if (wait && !ready) __builtin_amdgcn_s_sleep(1);
        }
        // exact 2-pass softmax scalars (all eij known; invalid = -3e38)
        float m = eij;
#pragma unroll
        for (int off = 32; off > 0; off >>= 1)
            m = fmaxf(m, __shfl_xor(m, off, 64));
        const float wt = valid ? __expf(eij - m) : 0.f;
        float s = wt, se = wt * ejraw;
#pragma unroll
        for (int off = 32; off > 0; off >>= 1) {
            s  += __shfl_xor(s,  off, 64);
            se += __shfl_xor(se, off, 64);
        }
        const float inv_s = (s > 0.f) ? (1.0f / s) : 0.f;

        // publish ej_new NOW — scalar-only payload, no drain needed
        {
            const float ejn = ejoc + ((s > 0.f) ? (se * inv_s - wkb) : 0.f);
            int bits = __float_as_int(ejn);
            if (bits == 0) bits = 1;   // avoid the not-ready sentinel
            if (lane == 0)
                __hip_atomic_store(&ej_new[id], bits,
                                   __ATOMIC_RELAXED, __HIP_MEMORY_SCOPE_AGENT);
        }

        // ---------------- phase B: row chain ----------------
        float4 acc0 = {0.f, 0.f, 0.f, 0.f};
        float4 acc1 = {0.f, 0.f, 0.f, 0.f};
        unsigned long long pend  = __ballot(valid && !isdep);
        unsigned long long wait2 = __ballot(isdep);

        while (pend | wait2) {
            if (!pend) {
                int rv = 0;
                const bool w = (wait2 >> lane) & 1ULL;
                if (w) rv = __hip_atomic_load(&row_flag[nbr], __ATOMIC_RELAXED,
                                              __HIP_MEMORY_SCOPE_AGENT);
                unsigned long long ready = __ballot(w && rv != 0);
                if (!ready) { __builtin_amdgcn_s_sleep(1); continue; }
                pend = ready;
                wait2 &= ~ready;
            }
            // take up to 8 ready neighbors; static indexing, duplicates
            // clamp to the last valid slot and get weight 0.
            int js_[8]; float ww[8]; int klast = 0;
#pragma unroll
            for (int t = 0; t < 8; ++t) {
                const bool has = (pend != 0);            // wave-uniform
                int k = has ? ((int)__ffsll(pend) - 1) : klast;
                if (has) pend &= pend - 1;
                klast = k;
                float w8 = __shfl(wt, k, 64);
                ww[t]  = has ? w8 : 0.f;
                js_[t] = __shfl(nbr, k, 64);
            }
            v4u pv8[8];
#pragma unroll
            for (int t = 0; t < 8; ++t) {
                const unsigned int* sp = ((js_[t] < id) ? out16 : feats16)
                                         + (size_t)js_[t] * DU16 + 4 * lane;
                pv8[t] = *(const v4u*)sp;
            }
#pragma unroll
            for (int t = 0; t < 8; ++t) {
                const float a = ww[t];
                float2 f0 = unpackh2(pv8[t].x), f1 = unpackh2(pv8[t].y);
                float2 f2 = unpackh2(pv8[t].z), f3 = unpackh2(pv8[t].w);
                acc0.x += a * f0.x; acc0.y += a * f0.y;
                acc0.z += a * f1.x; acc0.w += a * f1.y;
                acc1.x += a * f2.x; acc1.y += a * f2.y;
                acc1.z += a * f3.x; acc1.w += a * f3.y;
            }
        }

        float4 g0 = {c0.x + acc0.x * inv_s, c0.y + acc0.y * inv_s,
                     c0.z + acc0.z * inv_s, c0.w + acc0.w * inv_s};
        float4 g1 = {c1.x + acc1.x * inv_s, c1.y + acc1.y * inv_s,
                     c1.z + acc1.z * inv_s, c1.w + acc1.w * inv_s};

        // f16 mirror row: the gather payload, write-through + flag-ordered
        v4u pg;
        pg.x = packh2(g0.x, g0.y); pg.y = packh2(g0.z, g0.w);
        pg.z = packh2(g1.x, g1.y); pg.w = packh2(g1.z, g1.w);
        store_u4_llc(out16 + (size_t)id * DU16 + 4 * lane, pg);

        // order the out16 payload (at LLC) before the row flag
        __builtin_amdgcn_s_waitcnt(0);
        if (lane == 0)
            __hip_atomic_store(&row_flag[id], 1,
                               __ATOMIC_RELAXED, __HIP_MEMORY_SCOPE_AGENT);

        // f32 result row: no device consumer -> plain cached stores, off-chain
        float4* orow4 = (float4*)out + (size_t)id * D4;
        orow4[2 * lane]     = g0;
        orow4[2 * lane + 1] = g1;
    }
}

// ---------------- f32 fallback (verbatim R5 kernel, 260us verified) ---------
__global__ __launch_bounds__(256, 4) void attn_dataflow_f32(
    const float* __restrict__ feats,
    const int* __restrict__ neighbors, const int* __restrict__ deg,
    const float* __restrict__ ei_arr, const float* __restrict__ ej_orig,
    const float* __restrict__ wk_w, const float* __restrict__ wk_b,
    int* ej_new, float* out)
{
    const int lane   = threadIdx.x & 63;
    const int gwave  = (int)((blockIdx.x * blockDim.x + threadIdx.x) >> 6);
    const int nwaves = (int)((gridDim.x * blockDim.x) >> 6);
    const float4* f4  = (const float4*)feats;
    const float4* o4r = (const float4*)out;
    const float4* wk4 = (const float4*)wk_w;
    const float   wkb = wk_b[0];

    for (int id = gwave; id < NN; id += nwaves) {
        const int d = deg[id];
        int nbr = 0;
        if (lane < K) nbr = neighbors[(size_t)id * K + lane];
        const bool valid = lane < d;
        const bool isdep = valid && (nbr < id);

        const float4 c0 = f4[(size_t)id * D4 + lane];
        const float4 c1 = f4[(size_t)id * D4 + lane + 64];
        const float eii = ei_arr[id];

        float eij = 0.f;
        if (valid && !isdep) eij = eii * ej_orig[nbr];

        float4 acc0 = {0.f, 0.f, 0.f, 0.f};
        float4 acc1 = {0.f, 0.f, 0.f, 0.f};
        float m = -3.0e38f, s = 0.f;

        unsigned long long pend = __ballot(valid && !isdep);
        unsigned long long wait = __ballot(isdep);

        while (pend | wait) {
            if (!pend) {
                int pv = 0;
                const bool w = (wait >> lane) & 1ULL;
                if (w) pv = __hip_atomic_load(&ej_new[nbr], __ATOMIC_RELAXED,
                                              __HIP_MEMORY_SCOPE_AGENT);
                unsigned long long ready = __ballot(w && pv != 0);
                if (!ready) { __builtin_amdgcn_s_sleep(1); continue; }
                if (w && pv != 0) eij = eii * __int_as_float(pv);
                pend = ready;
                wait &= ~ready;
            }
            int cnt = 0;
            int   js[4]; float ee[4];
#pragma unroll
            for (int t = 0; t < 4; ++t) {
                if (pend) {
                    int k = (int)__ffsll(pend) - 1;
                    pend &= pend - 1;
                    ee[cnt] = __shfl(eij, k, 64);
                    js[cnt] = __shfl(nbr, k, 64);
                    ++cnt;
                }
            }
            float4 v0[4], v1[4];
#pragma unroll
            for (int t = 0; t < 4; ++t) {
                if (t < cnt) {
                    const float4* sp = (js[t] < id) ? (o4r + (size_t)js[t] * D4)
                                                    : (f4  + (size_t)js[t] * D4);
                    v0[t] = sp[lane];
                    v1[t] = sp[lane + 64];
                }
            }
            float mb = m;
#pragma unroll
            for (int t = 0; t < 4; ++t) if (t < cnt) mb = fmaxf(mb, ee[t]);
            if (mb > m) {
                const float r = __expf(m - mb);
                acc0.x *= r; acc0.y *= r; acc0.z *= r; acc0.w *= r;
                acc1.x *= r; acc1.y *= r; acc1.z *= r; acc1.w *= r;
                s *= r; m = mb;
            }
#pragma unroll
            for (int t = 0; t < 4; ++t) {
                if (t < cnt) {
                    const float wt = __expf(ee[t] - m);
                    s += wt;
                    acc0.x += wt * v0[t].x; acc0.y += wt * v0[t].y;
                    acc0.z += wt * v0[t].z; acc0.w += wt * v0[t].w;
                    acc1.x += wt * v1[t].x; acc1.y += wt * v1[t].y;
                    acc1.z += wt * v1[t].z; acc1.w += wt * v1[t].w;
                }
            }
        }

        const float inv_s = (s > 0.f) ? (1.0f / s) : 0.f;
        float4 g0 = {c0.x + acc0.x * inv_s, c0.y + acc0.y * inv_s,
                     c0.z + acc0.z * inv_s, c0.w + acc0.w * inv_s};
        float4 g1 = {c1.x + acc1.x * inv_s, c1.y + acc1.y * inv_s,
                     c1.z + acc1.z * inv_s, c1.w + acc1.w * inv_s};
        float* orow = out + (size_t)id * D;
        store_f4_llc(orow + 4 * lane,        g0);
        store_f4_llc(orow + 4 * (lane + 64), g1);

        float4 w0 = wk4[lane], w1 = wk4[lane + 64];
        float pd = g0.x * w0.x + g0.y * w0.y + g0.z * w0.z + g0.w * w0.w
                 + g1.x * w1.x + g1.y * w1.y + g1.z * w1.z + g1.w * w1.w;
#pragma unroll
        for (int off = 32; off > 0; off >>= 1)
            pd += __shfl_xor(pd, off, 64);

        int bits = __float_as_int(pd + wkb);
        if (bits == 0) bits = 1;

        __builtin_amdgcn_s_waitcnt(0);
        if (lane == 0)
            __hip_atomic_store(&ej_new[id], bits,
                               __ATOMIC_RELAXED, __HIP_MEMORY_SCOPE_AGENT);
    }
}

extern "C" void kernel_launch(void* const* d_in, const int* in_sizes, int n_in,
                              void* d_out, int out_size, void* d_ws, size_t ws_size,
                              hipStream_t stream)
{
    const float* feats     = (const float*)d_in[0];
    const float* wq_w      = (const float*)d_in[1];
    const float* wq_b      = (const float*)d_in[2];
    const float* wk_w      = (const float*)d_in[3];
    const float* wk_b      = (const float*)d_in[4];
    const int*   neighbors = (const int*)d_in[5];
    const int*   deg       = (const int*)d_in[6];
    float*       out       = (float*)d_out;

    // ws: [ej_new: NN i][pad 64][row_flag: NN i][pad 64][ei: NN f][ej_orig: NN f]
    //     | align1024 | [feats16: NN*1KB][out16: NN*1KB]  (if ws_size allows)
    char*  ws       = (char*)d_ws;
    int*   ej_new   = (int*)ws;
    int*   row_flag = ej_new + NN + 64;
    float* ei       = (float*)(row_flag + NN + 64);
    float* ej_orig  = ei + NN;
    size_t scal_end = (size_t)((char*)(ej_orig + NN) - ws);
    size_t f16_off  = (scal_end + 1023) & ~(size_t)1023;
    size_t f16_need = 2ull * NN * DU16 * sizeof(unsigned int);  // 102.4 MB
    const bool use16 = (ws_size >= f16_off + f16_need);
    unsigned int* feats16 = (unsigned int*)(ws + f16_off);
    unsigned int* out16   = feats16 + (size_t)NN * DU16;

    // zero ej_new + pad + row_flag
    (void)hipMemsetAsync(d_ws, 0, (size_t)(2 * NN + 128) * sizeof(int), stream);

    dim3 pb(256), pg((NN + 3) / 4);
    precomp_kernel<<<pg, pb, 0, stream>>>(feats, wq_w, wq_b, wk_w, wk_b,
                                          ei, ej_orig, use16 ? feats16 : nullptr);

    if (use16) {
        attn_dataflow_h16<<<dim3(1024), dim3(256), 0, stream>>>(
            feats, neighbors, deg, ei, ej_orig, wk_b,
            feats16, out16, ej_new, row_flag, out);
    } else {
        attn_dataflow_f32<<<dim3(1024), dim3(256), 0, stream>>>(
            feats, neighbors, deg, ei, ej_orig, wk_w, wk_b, ej_new, out);
    }
}

// Round 11
// 368.492 us; speedup vs baseline: 1.0328x; 1.0102x over previous
//
#include <hip/hip_runtime.h>
#include <hip/hip_fp16.h>

// Graph-attention sequential sweep as dataflow over the dependency DAG.
// Node i depends only on rows g[j] for j in neighbors[i], j<i, k<deg[i].
//
// R11 = R10 (verified 197.5us attn: decoupled scalar/row chains, no nt,
// f16 gather mirror) + ONE change: the CENTER row is read from feats16
// instead of f32 feats.
//  Theory (R10 traffic audit): FETCH 459MB vs ~160 ideal = ~300MB LLC
//  re-fetch of the gather pool; attn's allocation footprint was
//  102(f32 centers)+102(f16 pool)+153(writes) = 357MB >> 256MB LLC.
//  Dropping the f32-center stream cuts 102MB of direct fetch AND shrinks
//  the footprint to ~255MB ~= LLC so the pool can stay resident.
//  Precision: center f16 quantization ~1e-3 << existing 0.03125 absmax.
//
// Lessons encoded: R4 consecutive ids on distinct waves; R5 no global
// atomic counter; R6 max 16 waves/CU (LLC thrash), no precomp fusion;
// R7 f16 gather mirror; R8/R9 no nt hints; R10 scalar ej chain decoupled
// from row chain (keep: numerically cleaner, perf-neutral).
//
// Deadlock-freedom: all 4096 waves co-resident (4 blocks/CU x 256 CU, LDS=0,
// VGPR<=128 via __launch_bounds__(256,4)). Induction per sweep: smallest id
// with unpublished SCALAR has all scalar deps (<id) published -> progress;
// smallest id with unset ROW flag has all row deps (<id) set -> progress.
//
// Coherence (NO buffer_inv / NO buffer_wbl2):
//  - ej_new: scalar payload+flag word (bits==0 => not ready; +0.0 nudged to
//    denormal), relaxed agent atomic store/load, no ordering needed.
//  - out16 rows: write-through to LLC (sc0 sc1); row_flag set only after
//    s_waitcnt(0) drains the row; consumers read rows with NORMAL cached
//    loads, first touch only after row_flag seen -> no stale copies.

constexpr int NN   = 50000;
constexpr int D    = 512;
constexpr int K    = 32;
constexpr int D4   = D / 4;   // 128 float4 per f32 row
constexpr int DU16 = D / 2;   // 256 u32 per f16 row (512 halves)

typedef float        v4f __attribute__((ext_vector_type(4)));
typedef unsigned int v4u __attribute__((ext_vector_type(4)));

__device__ __forceinline__ void store_u4_llc(unsigned int* p, v4u v) {
    asm volatile("global_store_dwordx4 %0, %1, off sc0 sc1"
                 :: "v"(p), "v"(v) : "memory");
}
__device__ __forceinline__ void store_f4_llc(float* p, float4 v) {
    v4f vv; vv.x = v.x; vv.y = v.y; vv.z = v.z; vv.w = v.w;
    asm volatile("global_store_dwordx4 %0, %1, off sc0 sc1"
                 :: "v"(p), "v"(vv) : "memory");
}
__device__ __forceinline__ unsigned int packh2(float a, float b) {
    __half2 h = __floats2half2_rn(a, b);
    return *reinterpret_cast<unsigned int*>(&h);
}
__device__ __forceinline__ float2 unpackh2(unsigned int u) {
    __half2 h = *reinterpret_cast<__half2*>(&u);
    return __half22float2(h);
}

__global__ __launch_bounds__(256) void precomp_kernel(
    const float* __restrict__ feats,
    const float* __restrict__ wq_w, const float* __restrict__ wq_b,
    const float* __restrict__ wk_w, const float* __restrict__ wk_b,
    float* __restrict__ ei, float* __restrict__ ej_orig,
    unsigned int* __restrict__ feats16)   // may be null (f32 fallback path)
{
    int gw   = (int)((blockIdx.x * blockDim.x + threadIdx.x) >> 6); // global wave id
    int lane = threadIdx.x & 63;
    if (gw >= NN) return;
    const float4* row = (const float4*)feats + (size_t)gw * D4;
    const float4* q4  = (const float4*)wq_w;
    const float4* k4  = (const float4*)wk_w;
    // lane owns elements [8*lane .. 8*lane+7]
    float4 v0 = row[2 * lane], v1 = row[2 * lane + 1];
    float4 q0 = q4[2 * lane],  q1 = q4[2 * lane + 1];
    float4 k0 = k4[2 * lane],  k1 = k4[2 * lane + 1];
    float dq = v0.x*q0.x + v0.y*q0.y + v0.z*q0.z + v0.w*q0.w
             + v1.x*q1.x + v1.y*q1.y + v1.z*q1.z + v1.w*q1.w;
    float dk = v0.x*k0.x + v0.y*k0.y + v0.z*k0.z + v0.w*k0.w
             + v1.x*k1.x + v1.y*k1.y + v1.z*k1.z + v1.w*k1.w;
#pragma unroll
    for (int off = 32; off > 0; off >>= 1) {
        dq += __shfl_down(dq, off, 64);
        dk += __shfl_down(dk, off, 64);
    }
    if (feats16) {
        v4u p;
        p.x = packh2(v0.x, v0.y); p.y = packh2(v0.z, v0.w);
        p.z = packh2(v1.x, v1.y); p.w = packh2(v1.z, v1.w);
        *(v4u*)(feats16 + (size_t)gw * DU16 + 4 * lane) = p;  // plain store;
        // visible to the attn kernel via stream-order kernel boundary.
    }
    if (lane == 0) {
        ei[gw]      = dq + wq_b[0];
        ej_orig[gw] = dk + wk_b[0];
    }
}

// ---------------- fp16-gather dataflow kernel (primary path) ----------------
__global__ __launch_bounds__(256, 4) void attn_dataflow_h16(
    const int* __restrict__ neighbors, const int* __restrict__ deg,
    const float* __restrict__ ei_arr, const float* __restrict__ ej_orig,
    const float* __restrict__ wk_b,
    const unsigned int* __restrict__ feats16, unsigned int* __restrict__ out16,
    int* ej_new, int* row_flag, float* out)
{
    const int lane   = threadIdx.x & 63;
    const int gwave  = (int)((blockIdx.x * blockDim.x + threadIdx.x) >> 6);
    const int nwaves = (int)((gridDim.x * blockDim.x) >> 6);
    const float   wkb = wk_b[0];

    for (int id = gwave; id < NN; id += nwaves) {
        const int d = deg[id];
        int nbr = 0;
        if (lane < K) nbr = neighbors[(size_t)id * K + lane];
        const bool valid = lane < d;                 // d <= 32
        const bool isdep = valid && (nbr < id);

        // center row from the f16 mirror (16B/lane, removes the f32 feats
        // stream from this kernel's LLC footprint entirely — R11 change)
        const v4u cp = *(const v4u*)(feats16 + (size_t)id * DU16 + 4 * lane);
        float2 cf0 = unpackh2(cp.x), cf1 = unpackh2(cp.y);
        float2 cf2 = unpackh2(cp.z), cf3 = unpackh2(cp.w);
        const float4 c0 = {cf0.x, cf0.y, cf1.x, cf1.y};
        const float4 c1 = {cf2.x, cf2.y, cf3.x, cf3.y};
        const float eii  = ei_arr[id];
        const float ejoc = ej_orig[id];   // own w_k(feats[id]) — exact

        float ejraw = 0.f, eij = -3.0e38f;
        if (valid && !isdep) { ejraw = ej_orig[nbr]; eij = eii * ejraw; }

        // ---------------- phase A: scalar chain ----------------
        unsigned long long wait = __ballot(isdep);
        while (wait) {
            int pv = 0;
            const bool w = (wait >> lane) & 1ULL;
            if (w) pv = __hip_atomic_load(&ej_new[nbr], __ATOMIC_RELAXED,
                                          __HIP_MEMORY_SCOPE_AGENT);
            unsigned long long ready = __ballot(w && pv != 0);
            if (w && pv != 0) { ejraw = __int_as_float(pv); eij = eii * ejraw; }
            wait &= ~ready;
            if (wait && !ready) __builtin_amdgcn_s_sleep(1);
        }
        // exact 2-pass softmax scalars (all eij known; invalid = -3e38)
        float m = eij;
#pragma unroll
        for (int off = 32; off > 0; off >>= 1)
            m = fmaxf(m, __shfl_xor(m, off, 64));
        const float wt = valid ? __expf(eij - m) : 0.f;
        float s = wt, se = wt * ejraw;
#pragma unroll
        for (int off = 32; off > 0; off >>= 1) {
            s  += __shfl_xor(s,  off, 64);
            se += __shfl_xor(se, off, 64);
        }
        const float inv_s = (s > 0.f) ? (1.0f / s) : 0.f;

        // publish ej_new NOW — scalar-only payload, no drain needed
        {
            const float ejn = ejoc + ((s > 0.f) ? (se * inv_s - wkb) : 0.f);
            int bits = __float_as_int(ejn);
            if (bits == 0) bits = 1;   // avoid the not-ready sentinel
            if (lane == 0)
                __hip_atomic_store(&ej_new[id], bits,
                                   __ATOMIC_RELAXED, __HIP_MEMORY_SCOPE_AGENT);
        }

        // ---------------- phase B: row chain ----------------
        float4 acc0 = {0.f, 0.f, 0.f, 0.f};
        float4 acc1 = {0.f, 0.f, 0.f, 0.f};
        unsigned long long pend  = __ballot(valid && !isdep);
        unsigned long long wait2 = __ballot(isdep);

        while (pend | wait2) {
            if (!pend) {
                int rv = 0;
                const bool w = (wait2 >> lane) & 1ULL;
                if (w) rv = __hip_atomic_load(&row_flag[nbr], __ATOMIC_RELAXED,
                                              __HIP_MEMORY_SCOPE_AGENT);
                unsigned long long ready = __ballot(w && rv != 0);
                if (!ready) { __builtin_amdgcn_s_sleep(1); continue; }
                pend = ready;
                wait2 &= ~ready;
            }
            // take up to 8 ready neighbors; static indexing, duplicates
            // clamp to the last valid slot and get weight 0.
            int js_[8]; float ww[8]; int klast = 0;
#pragma unroll
            for (int t = 0; t < 8; ++t) {
                const bool has = (pend != 0);            // wave-uniform
                int k = has ? ((int)__ffsll(pend) - 1) : klast;
                if (has) pend &= pend - 1;
                klast = k;
                float w8 = __shfl(wt, k, 64);
                ww[t]  = has ? w8 : 0.f;
                js_[t] = __shfl(nbr, k, 64);
            }
            v4u pv8[8];
#pragma unroll
            for (int t = 0; t < 8; ++t) {
                const unsigned int* sp = ((js_[t] < id) ? out16 : feats16)
                                         + (size_t)js_[t] * DU16 + 4 * lane;
                pv8[t] = *(const v4u*)sp;
            }
#pragma unroll
            for (int t = 0; t < 8; ++t) {
                const float a = ww[t];
                float2 f0 = unpackh2(pv8[t].x), f1 = unpackh2(pv8[t].y);
                float2 f2 = unpackh2(pv8[t].z), f3 = unpackh2(pv8[t].w);
                acc0.x += a * f0.x; acc0.y += a * f0.y;
                acc0.z += a * f1.x; acc0.w += a * f1.y;
                acc1.x += a * f2.x; acc1.y += a * f2.y;
                acc1.z += a * f3.x; acc1.w += a * f3.y;
            }
        }

        float4 g0 = {c0.x + acc0.x * inv_s, c0.y + acc0.y * inv_s,
                     c0.z + acc0.z * inv_s, c0.w + acc0.w * inv_s};
        float4 g1 = {c1.x + acc1.x * inv_s, c1.y + acc1.y * inv_s,
                     c1.z + acc1.z * inv_s, c1.w + acc1.w * inv_s};

        // f16 mirror row: the gather payload, write-through + flag-ordered
        v4u pg;
        pg.x = packh2(g0.x, g0.y); pg.y = packh2(g0.z, g0.w);
        pg.z = packh2(g1.x, g1.y); pg.w = packh2(g1.z, g1.w);
        store_u4_llc(out16 + (size_t)id * DU16 + 4 * lane, pg);

        // order the out16 payload (at LLC) before the row flag
        __builtin_amdgcn_s_waitcnt(0);
        if (lane == 0)
            __hip_atomic_store(&row_flag[id], 1,
                               __ATOMIC_RELAXED, __HIP_MEMORY_SCOPE_AGENT);

        // f32 result row: no device consumer -> plain cached stores, off-chain
        float4* orow4 = (float4*)out + (size_t)id * D4;
        orow4[2 * lane]     = g0;
        orow4[2 * lane + 1] = g1;
    }
}

// ---------------- f32 fallback (verbatim R5 kernel, 260us verified) ---------
__global__ __launch_bounds__(256, 4) void attn_dataflow_f32(
    const float* __restrict__ feats,
    const int* __restrict__ neighbors, const int* __restrict__ deg,
    const float* __restrict__ ei_arr, const float* __restrict__ ej_orig,
    const float* __restrict__ wk_w, const float* __restrict__ wk_b,
    int* ej_new, float* out)
{
    const int lane   = threadIdx.x & 63;
    const int gwave  = (int)((blockIdx.x * blockDim.x + threadIdx.x) >> 6);
    const int nwaves = (int)((gridDim.x * blockDim.x) >> 6);
    const float4* f4  = (const float4*)feats;
    const float4* o4r = (const float4*)out;
    const float4* wk4 = (const float4*)wk_w;
    const float   wkb = wk_b[0];

    for (int id = gwave; id < NN; id += nwaves) {
        const int d = deg[id];
        int nbr = 0;
        if (lane < K) nbr = neighbors[(size_t)id * K + lane];
        const bool valid = lane < d;
        const bool isdep = valid && (nbr < id);

        const float4 c0 = f4[(size_t)id * D4 + lane];
        const float4 c1 = f4[(size_t)id * D4 + lane + 64];
        const float eii = ei_arr[id];

        float eij = 0.f;
        if (valid && !isdep) eij = eii * ej_orig[nbr];

        float4 acc0 = {0.f, 0.f, 0.f, 0.f};
        float4 acc1 = {0.f, 0.f, 0.f, 0.f};
        float m = -3.0e38f, s = 0.f;

        unsigned long long pend = __ballot(valid && !isdep);
        unsigned long long wait = __ballot(isdep);

        while (pend | wait) {
            if (!pend) {
                int pv = 0;
                const bool w = (wait >> lane) & 1ULL;
                if (w) pv = __hip_atomic_load(&ej_new[nbr], __ATOMIC_RELAXED,
                                              __HIP_MEMORY_SCOPE_AGENT);
                unsigned long long ready = __ballot(w && pv != 0);
                if (!ready) { __builtin_amdgcn_s_sleep(1); continue; }
                if (w && pv != 0) eij = eii * __int_as_float(pv);
                pend = ready;
                wait &= ~ready;
            }
            int cnt = 0;
            int   js[4]; float ee[4];
#pragma unroll
            for (int t = 0; t < 4; ++t) {
                if (pend) {
                    int k = (int)__ffsll(pend) - 1;
                    pend &= pend - 1;
                    ee[cnt] = __shfl(eij, k, 64);
                    js[cnt] = __shfl(nbr, k, 64);
                    ++cnt;
                }
            }
            float4 v0[4], v1[4];
#pragma unroll
            for (int t = 0; t < 4; ++t) {
                if (t < cnt) {
                    const float4* sp = (js[t] < id) ? (o4r + (size_t)js[t] * D4)
                                                    : (f4  + (size_t)js[t] * D4);
                    v0[t] = sp[lane];
                    v1[t] = sp[lane + 64];
                }
            }
            float mb = m;
#pragma unroll
            for (int t = 0; t < 4; ++t) if (t < cnt) mb = fmaxf(mb, ee[t]);
            if (mb > m) {
                const float r = __expf(m - mb);
                acc0.x *= r; acc0.y *= r; acc0.z *= r; acc0.w *= r;
                acc1.x *= r; acc1.y *= r; acc1.z *= r; acc1.w *= r;
                s *= r; m = mb;
            }
#pragma unroll
            for (int t = 0; t < 4; ++t) {
                if (t < cnt) {
                    const float wt = __expf(ee[t] - m);
                    s += wt;
                    acc0.x += wt * v0[t].x; acc0.y += wt * v0[t].y;
                    acc0.z += wt * v0[t].z; acc0.w += wt * v0[t].w;
                    acc1.x += wt * v1[t].x; acc1.y += wt * v1[t].y;
                    acc1.z += wt * v1[t].z; acc1.w += wt * v1[t].w;
                }
            }
        }

        const float inv_s = (s > 0.f) ? (1.0f / s) : 0.f;
        float4 g0 = {c0.x + acc0.x * inv_s, c0.y + acc0.y * inv_s,
                     c0.z + acc0.z * inv_s, c0.w + acc0.w * inv_s};
        float4 g1 = {c1.x + acc1.x * inv_s, c1.y + acc1.y * inv_s,
                     c1.z + acc1.z * inv_s, c1.w + acc1.w * inv_s};
        float* orow = out + (size_t)id * D;
        store_f4_llc(orow + 4 * lane,        g0);
        store_f4_llc(orow + 4 * (lane + 64), g1);

        float4 w0 = wk4[lane], w1 = wk4[lane + 64];
        float pd = g0.x * w0.x + g0.y * w0.y + g0.z * w0.z + g0.w * w0.w
                 + g1.x * w1.x + g1.y * w1.y + g1.z * w1.z + g1.w * w1.w;
#pragma unroll
        for (int off = 32; off > 0; off >>= 1)
            pd += __shfl_xor(pd, off, 64);

        int bits = __float_as_int(pd + wkb);
        if (bits == 0) bits = 1;

        __builtin_amdgcn_s_waitcnt(0);
        if (lane == 0)
            __hip_atomic_store(&ej_new[id], bits,
                               __ATOMIC_RELAXED, __HIP_MEMORY_SCOPE_AGENT);
    }
}

extern "C" void kernel_launch(void* const* d_in, const int* in_sizes, int n_in,
                              void* d_out, int out_size, void* d_ws, size_t ws_size,
                              hipStream_t stream)
{
    const float* feats     = (const float*)d_in[0];
    const float* wq_w      = (const float*)d_in[1];
    const float* wq_b      = (const float*)d_in[2];
    const float* wk_w      = (const float*)d_in[3];
    const float* wk_b      = (const float*)d_in[4];
    const int*   neighbors = (const int*)d_in[5];
    const int*   deg       = (const int*)d_in[6];
    float*       out       = (float*)d_out;

    // ws: [ej_new: NN i][pad 64][row_flag: NN i][pad 64][ei: NN f][ej_orig: NN f]
    //     | align1024 | [feats16: NN*1KB][out16: NN*1KB]  (if ws_size allows)
    char*  ws       = (char*)d_ws;
    int*   ej_new   = (int*)ws;
    int*   row_flag = ej_new + NN + 64;
    float* ei       = (float*)(row_flag + NN + 64);
    float* ej_orig  = ei + NN;
    size_t scal_end = (size_t)((char*)(ej_orig + NN) - ws);
    size_t f16_off  = (scal_end + 1023) & ~(size_t)1023;
    size_t f16_need = 2ull * NN * DU16 * sizeof(unsigned int);  // 102.4 MB
    const bool use16 = (ws_size >= f16_off + f16_need);
    unsigned int* feats16 = (unsigned int*)(ws + f16_off);
    unsigned int* out16   = feats16 + (size_t)NN * DU16;

    // zero ej_new + pad + row_flag
    (void)hipMemsetAsync(d_ws, 0, (size_t)(2 * NN + 128) * sizeof(int), stream);

    dim3 pb(256), pg((NN + 3) / 4);
    precomp_kernel<<<pg, pb, 0, stream>>>(feats, wq_w, wq_b, wk_w, wk_b,
                                          ei, ej_orig, use16 ? feats16 : nullptr);

    if (use16) {
        attn_dataflow_h16<<<dim3(1024), dim3(256), 0, stream>>>(
            neighbors, deg, ei, ej_orig, wk_b,
            feats16, out16, ej_new, row_flag, out);
    } else {
        attn_dataflow_f32<<<dim3(1024), dim3(256), 0, stream>>>(
            feats, neighbors, deg, ei, ej_orig, wk_w, wk_b, ej_new, out);
    }
}

// Round 12
// 365.878 us; speedup vs baseline: 1.0402x; 1.0071x over previous
//
#include <hip/hip_runtime.h>
#include <hip/hip_fp16.h>

// Graph-attention sequential sweep as dataflow over the dependency DAG.
// Node i depends only on rows g[j] for j in neighbors[i], j<i, k<deg[i].
//
// R12 = R11 (verified 189us attn: f16-only gather+center pool, decoupled
// scalar/row chains) + ONE change: the f32 `out` row stores are issued
// NON-TEMPORALLY (they are write-once, never read on-device, and already
// sit AFTER the row_flag publish, off the dependency chain since R10).
//  Theory: dur is bytes-proportional at a pinned ~3.15 TB/s (R7-R11) and
//  FETCH is ~370MB above ideal = f16 pool re-fetch. The last big
//  LLC-allocating stream is out f32 (102MB write-once dirty lines);
//  footprint 255MB ~= LLC. If nt stores bypass LLC allocation, the pool
//  (102MB) finally stays resident and the re-fetch collapses.
//  R8 could NOT rule on this: its nt stores were confounded with nt
//  center-LOADS (latency cost) and sat before the publish drain.
//
// Lessons encoded: R4 consecutive ids on distinct waves; R5 no global
// atomic counter; R6 max 16 waves/CU, no precomp fusion; R7 f16 gather
// mirror; R8 no nt on LOADS of cached-resident data; R10 scalar ej chain
// decoupled; R11 center row from feats16.
//
// Deadlock-freedom: all 4096 waves co-resident (4 blocks/CU x 256 CU, LDS=0,
// VGPR<=128 via __launch_bounds__(256,4)). Induction per sweep: smallest id
// with unpublished SCALAR has all scalar deps (<id) published -> progress;
// smallest id with unset ROW flag has all row deps (<id) set -> progress.
//
// Coherence (NO buffer_inv / NO buffer_wbl2):
//  - ej_new: scalar payload+flag word (bits==0 => not ready; +0.0 nudged to
//    denormal), relaxed agent atomic store/load, no ordering needed.
//  - out16 rows: write-through to LLC (sc0 sc1); row_flag set only after
//    s_waitcnt(0) drains the row; consumers read rows with NORMAL cached
//    loads, first touch only after row_flag seen -> no stale copies.
//  - out f32: nt stores, no device consumer; host visibility via kernel-end
//    drain (release at stream boundary).

constexpr int NN   = 50000;
constexpr int D    = 512;
constexpr int K    = 32;
constexpr int D4   = D / 4;   // 128 float4 per f32 row
constexpr int DU16 = D / 2;   // 256 u32 per f16 row (512 halves)

typedef float        v4f __attribute__((ext_vector_type(4)));
typedef unsigned int v4u __attribute__((ext_vector_type(4)));

__device__ __forceinline__ void store_u4_llc(unsigned int* p, v4u v) {
    asm volatile("global_store_dwordx4 %0, %1, off sc0 sc1"
                 :: "v"(p), "v"(v) : "memory");
}
__device__ __forceinline__ void store_f4_llc(float* p, float4 v) {
    v4f vv; vv.x = v.x; vv.y = v.y; vv.z = v.z; vv.w = v.w;
    asm volatile("global_store_dwordx4 %0, %1, off sc0 sc1"
                 :: "v"(p), "v"(vv) : "memory");
}
__device__ __forceinline__ void store_f4_nt(float4* p, float4 v) {
    v4f vv; vv.x = v.x; vv.y = v.y; vv.z = v.z; vv.w = v.w;
    __builtin_nontemporal_store(vv, (v4f*)p);
}
__device__ __forceinline__ unsigned int packh2(float a, float b) {
    __half2 h = __floats2half2_rn(a, b);
    return *reinterpret_cast<unsigned int*>(&h);
}
__device__ __forceinline__ float2 unpackh2(unsigned int u) {
    __half2 h = *reinterpret_cast<__half2*>(&u);
    return __half22float2(h);
}

__global__ __launch_bounds__(256) void precomp_kernel(
    const float* __restrict__ feats,
    const float* __restrict__ wq_w, const float* __restrict__ wq_b,
    const float* __restrict__ wk_w, const float* __restrict__ wk_b,
    float* __restrict__ ei, float* __restrict__ ej_orig,
    unsigned int* __restrict__ feats16)   // may be null (f32 fallback path)
{
    int gw   = (int)((blockIdx.x * blockDim.x + threadIdx.x) >> 6); // global wave id
    int lane = threadIdx.x & 63;
    if (gw >= NN) return;
    const float4* row = (const float4*)feats + (size_t)gw * D4;
    const float4* q4  = (const float4*)wq_w;
    const float4* k4  = (const float4*)wk_w;
    // lane owns elements [8*lane .. 8*lane+7]
    float4 v0 = row[2 * lane], v1 = row[2 * lane + 1];
    float4 q0 = q4[2 * lane],  q1 = q4[2 * lane + 1];
    float4 k0 = k4[2 * lane],  k1 = k4[2 * lane + 1];
    float dq = v0.x*q0.x + v0.y*q0.y + v0.z*q0.z + v0.w*q0.w
             + v1.x*q1.x + v1.y*q1.y + v1.z*q1.z + v1.w*q1.w;
    float dk = v0.x*k0.x + v0.y*k0.y + v0.z*k0.z + v0.w*k0.w
             + v1.x*k1.x + v1.y*k1.y + v1.z*k1.z + v1.w*k1.w;
#pragma unroll
    for (int off = 32; off > 0; off >>= 1) {
        dq += __shfl_down(dq, off, 64);
        dk += __shfl_down(dk, off, 64);
    }
    if (feats16) {
        v4u p;
        p.x = packh2(v0.x, v0.y); p.y = packh2(v0.z, v0.w);
        p.z = packh2(v1.x, v1.y); p.w = packh2(v1.z, v1.w);
        *(v4u*)(feats16 + (size_t)gw * DU16 + 4 * lane) = p;  // plain store;
        // visible to the attn kernel via stream-order kernel boundary.
    }
    if (lane == 0) {
        ei[gw]      = dq + wq_b[0];
        ej_orig[gw] = dk + wk_b[0];
    }
}

// ---------------- fp16-gather dataflow kernel (primary path) ----------------
__global__ __launch_bounds__(256, 4) void attn_dataflow_h16(
    const int* __restrict__ neighbors, const int* __restrict__ deg,
    const float* __restrict__ ei_arr, const float* __restrict__ ej_orig,
    const float* __restrict__ wk_b,
    const unsigned int* __restrict__ feats16, unsigned int* __restrict__ out16,
    int* ej_new, int* row_flag, float* out)
{
    const int lane   = threadIdx.x & 63;
    const int gwave  = (int)((blockIdx.x * blockDim.x + threadIdx.x) >> 6);
    const int nwaves = (int)((gridDim.x * blockDim.x) >> 6);
    const float   wkb = wk_b[0];

    for (int id = gwave; id < NN; id += nwaves) {
        const int d = deg[id];
        int nbr = 0;
        if (lane < K) nbr = neighbors[(size_t)id * K + lane];
        const bool valid = lane < d;                 // d <= 32
        const bool isdep = valid && (nbr < id);

        // center row from the f16 mirror (16B/lane; no f32 feats stream here)
        const v4u cp = *(const v4u*)(feats16 + (size_t)id * DU16 + 4 * lane);
        float2 cf0 = unpackh2(cp.x), cf1 = unpackh2(cp.y);
        float2 cf2 = unpackh2(cp.z), cf3 = unpackh2(cp.w);
        const float4 c0 = {cf0.x, cf0.y, cf1.x, cf1.y};
        const float4 c1 = {cf2.x, cf2.y, cf3.x, cf3.y};
        const float eii  = ei_arr[id];
        const float ejoc = ej_orig[id];   // own w_k(feats[id]) — exact

        float ejraw = 0.f, eij = -3.0e38f;
        if (valid && !isdep) { ejraw = ej_orig[nbr]; eij = eii * ejraw; }

        // ---------------- phase A: scalar chain ----------------
        unsigned long long wait = __ballot(isdep);
        while (wait) {
            int pv = 0;
            const bool w = (wait >> lane) & 1ULL;
            if (w) pv = __hip_atomic_load(&ej_new[nbr], __ATOMIC_RELAXED,
                                          __HIP_MEMORY_SCOPE_AGENT);
            unsigned long long ready = __ballot(w && pv != 0);
            if (w && pv != 0) { ejraw = __int_as_float(pv); eij = eii * ejraw; }
            wait &= ~ready;
            if (wait && !ready) __builtin_amdgcn_s_sleep(1);
        }
        // exact 2-pass softmax scalars (all eij known; invalid = -3e38)
        float m = eij;
#pragma unroll
        for (int off = 32; off > 0; off >>= 1)
            m = fmaxf(m, __shfl_xor(m, off, 64));
        const float wt = valid ? __expf(eij - m) : 0.f;
        float s = wt, se = wt * ejraw;
#pragma unroll
        for (int off = 32; off > 0; off >>= 1) {
            s  += __shfl_xor(s,  off, 64);
            se += __shfl_xor(se, off, 64);
        }
        const float inv_s = (s > 0.f) ? (1.0f / s) : 0.f;

        // publish ej_new NOW — scalar-only payload, no drain needed
        {
            const float ejn = ejoc + ((s > 0.f) ? (se * inv_s - wkb) : 0.f);
            int bits = __float_as_int(ejn);
            if (bits == 0) bits = 1;   // avoid the not-ready sentinel
            if (lane == 0)
                __hip_atomic_store(&ej_new[id], bits,
                                   __ATOMIC_RELAXED, __HIP_MEMORY_SCOPE_AGENT);
        }

        // ---------------- phase B: row chain ----------------
        float4 acc0 = {0.f, 0.f, 0.f, 0.f};
        float4 acc1 = {0.f, 0.f, 0.f, 0.f};
        unsigned long long pend  = __ballot(valid && !isdep);
        unsigned long long wait2 = __ballot(isdep);

        while (pend | wait2) {
            if (!pend) {
                int rv = 0;
                const bool w = (wait2 >> lane) & 1ULL;
                if (w) rv = __hip_atomic_load(&row_flag[nbr], __ATOMIC_RELAXED,
                                              __HIP_MEMORY_SCOPE_AGENT);
                unsigned long long ready = __ballot(w && rv != 0);
                if (!ready) { __builtin_amdgcn_s_sleep(1); continue; }
                pend = ready;
                wait2 &= ~ready;
            }
            // take up to 8 ready neighbors; static indexing, duplicates
            // clamp to the last valid slot and get weight 0.
            int js_[8]; float ww[8]; int klast = 0;
#pragma unroll
            for (int t = 0; t < 8; ++t) {
                const bool has = (pend != 0);            // wave-uniform
                int k = has ? ((int)__ffsll(pend) - 1) : klast;
                if (has) pend &= pend - 1;
                klast = k;
                float w8 = __shfl(wt, k, 64);
                ww[t]  = has ? w8 : 0.f;
                js_[t] = __shfl(nbr, k, 64);
            }
            v4u pv8[8];
#pragma unroll
            for (int t = 0; t < 8; ++t) {
                const unsigned int* sp = ((js_[t] < id) ? out16 : feats16)
                                         + (size_t)js_[t] * DU16 + 4 * lane;
                pv8[t] = *(const v4u*)sp;
            }
#pragma unroll
            for (int t = 0; t < 8; ++t) {
                const float a = ww[t];
                float2 f0 = unpackh2(pv8[t].x), f1 = unpackh2(pv8[t].y);
                float2 f2 = unpackh2(pv8[t].z), f3 = unpackh2(pv8[t].w);
                acc0.x += a * f0.x; acc0.y += a * f0.y;
                acc0.z += a * f1.x; acc0.w += a * f1.y;
                acc1.x += a * f2.x; acc1.y += a * f2.y;
                acc1.z += a * f3.x; acc1.w += a * f3.y;
            }
        }

        float4 g0 = {c0.x + acc0.x * inv_s, c0.y + acc0.y * inv_s,
                     c0.z + acc0.z * inv_s, c0.w + acc0.w * inv_s};
        float4 g1 = {c1.x + acc1.x * inv_s, c1.y + acc1.y * inv_s,
                     c1.z + acc1.z * inv_s, c1.w + acc1.w * inv_s};

        // f16 mirror row: the gather payload, write-through + flag-ordered
        v4u pg;
        pg.x = packh2(g0.x, g0.y); pg.y = packh2(g0.z, g0.w);
        pg.z = packh2(g1.x, g1.y); pg.w = packh2(g1.z, g1.w);
        store_u4_llc(out16 + (size_t)id * DU16 + 4 * lane, pg);

        // order the out16 payload (at LLC) before the row flag
        __builtin_amdgcn_s_waitcnt(0);
        if (lane == 0)
            __hip_atomic_store(&row_flag[id], 1,
                               __ATOMIC_RELAXED, __HIP_MEMORY_SCOPE_AGENT);

        // f32 result row: no device consumer, off-chain since R10.
        // R12: NON-TEMPORAL — write-once stream must not evict the f16 pool.
        float4* orow4 = (float4*)out + (size_t)id * D4;
        store_f4_nt(orow4 + 2 * lane,     g0);
        store_f4_nt(orow4 + 2 * lane + 1, g1);
    }
}

// ---------------- f32 fallback (verbatim R5 kernel, 260us verified) ---------
__global__ __launch_bounds__(256, 4) void attn_dataflow_f32(
    const float* __restrict__ feats,
    const int* __restrict__ neighbors, const int* __restrict__ deg,
    const float* __restrict__ ei_arr, const float* __restrict__ ej_orig,
    const float* __restrict__ wk_w, const float* __restrict__ wk_b,
    int* ej_new, float* out)
{
    const int lane   = threadIdx.x & 63;
    const int gwave  = (int)((blockIdx.x * blockDim.x + threadIdx.x) >> 6);
    const int nwaves = (int)((gridDim.x * blockDim.x) >> 6);
    const float4* f4  = (const float4*)feats;
    const float4* o4r = (const float4*)out;
    const float4* wk4 = (const float4*)wk_w;
    const float   wkb = wk_b[0];

    for (int id = gwave; id < NN; id += nwaves) {
        const int d = deg[id];
        int nbr = 0;
        if (lane < K) nbr = neighbors[(size_t)id * K + lane];
        const bool valid = lane < d;
        const bool isdep = valid && (nbr < id);

        const float4 c0 = f4[(size_t)id * D4 + lane];
        const float4 c1 = f4[(size_t)id * D4 + lane + 64];
        const float eii = ei_arr[id];

        float eij = 0.f;
        if (valid && !isdep) eij = eii * ej_orig[nbr];

        float4 acc0 = {0.f, 0.f, 0.f, 0.f};
        float4 acc1 = {0.f, 0.f, 0.f, 0.f};
        float m = -3.0e38f, s = 0.f;

        unsigned long long pend = __ballot(valid && !isdep);
        unsigned long long wait = __ballot(isdep);

        while (pend | wait) {
            if (!pend) {
                int pv = 0;
                const bool w = (wait >> lane) & 1ULL;
                if (w) pv = __hip_atomic_load(&ej_new[nbr], __ATOMIC_RELAXED,
                                              __HIP_MEMORY_SCOPE_AGENT);
                unsigned long long ready = __ballot(w && pv != 0);
                if (!ready) { __builtin_amdgcn_s_sleep(1); continue; }
                if (w && pv != 0) eij = eii * __int_as_float(pv);
                pend = ready;
                wait &= ~ready;
            }
            int cnt = 0;
            int   js[4]; float ee[4];
#pragma unroll
            for (int t = 0; t < 4; ++t) {
                if (pend) {
                    int k = (int)__ffsll(pend) - 1;
                    pend &= pend - 1;
                    ee[cnt] = __shfl(eij, k, 64);
                    js[cnt] = __shfl(nbr, k, 64);
                    ++cnt;
                }
            }
            float4 v0[4], v1[4];
#pragma unroll
            for (int t = 0; t < 4; ++t) {
                if (t < cnt) {
                    const float4* sp = (js[t] < id) ? (o4r + (size_t)js[t] * D4)
                                                    : (f4  + (size_t)js[t] * D4);
                    v0[t] = sp[lane];
                    v1[t] = sp[lane + 64];
                }
            }
            float mb = m;
#pragma unroll
            for (int t = 0; t < 4; ++t) if (t < cnt) mb = fmaxf(mb, ee[t]);
            if (mb > m) {
                const float r = __expf(m - mb);
                acc0.x *= r; acc0.y *= r; acc0.z *= r; acc0.w *= r;
                acc1.x *= r; acc1.y *= r; acc1.z *= r; acc1.w *= r;
                s *= r; m = mb;
            }
#pragma unroll
            for (int t = 0; t < 4; ++t) {
                if (t < cnt) {
                    const float wt = __expf(ee[t] - m);
                    s += wt;
                    acc0.x += wt * v0[t].x; acc0.y += wt * v0[t].y;
                    acc0.z += wt * v0[t].z; acc0.w += wt * v0[t].w;
                    acc1.x += wt * v1[t].x; acc1.y += wt * v1[t].y;
                    acc1.z += wt * v1[t].z; acc1.w += wt * v1[t].w;
                }
            }
        }

        const float inv_s = (s > 0.f) ? (1.0f / s) : 0.f;
        float4 g0 = {c0.x + acc0.x * inv_s, c0.y + acc0.y * inv_s,
                     c0.z + acc0.z * inv_s, c0.w + acc0.w * inv_s};
        float4 g1 = {c1.x + acc1.x * inv_s, c1.y + acc1.y * inv_s,
                     c1.z + acc1.z * inv_s, c1.w + acc1.w * inv_s};
        float* orow = out + (size_t)id * D;
        store_f4_llc(orow + 4 * lane,        g0);
        store_f4_llc(orow + 4 * (lane + 64), g1);

        float4 w0 = wk4[lane], w1 = wk4[lane + 64];
        float pd = g0.x * w0.x + g0.y * w0.y + g0.z * w0.z + g0.w * w0.w
                 + g1.x * w1.x + g1.y * w1.y + g1.z * w1.z + g1.w * w1.w;
#pragma unroll
        for (int off = 32; off > 0; off >>= 1)
            pd += __shfl_xor(pd, off, 64);

        int bits = __float_as_int(pd + wkb);
        if (bits == 0) bits = 1;

        __builtin_amdgcn_s_waitcnt(0);
        if (lane == 0)
            __hip_atomic_store(&ej_new[id], bits,
                               __ATOMIC_RELAXED, __HIP_MEMORY_SCOPE_AGENT);
    }
}

extern "C" void kernel_launch(void* const* d_in, const int* in_sizes, int n_in,
                              void* d_out, int out_size, void* d_ws, size_t ws_size,
                              hipStream_t stream)
{
    const float* feats     = (const float*)d_in[0];
    const float* wq_w      = (const float*)d_in[1];
    const float* wq_b      = (const float*)d_in[2];
    const float* wk_w      = (const float*)d_in[3];
    const float* wk_b      = (const float*)d_in[4];
    const int*   neighbors = (const int*)d_in[5];
    const int*   deg       = (const int*)d_in[6];
    float*       out       = (float*)d_out;

    // ws: [ej_new: NN i][pad 64][row_flag: NN i][pad 64][ei: NN f][ej_orig: NN f]
    //     | align1024 | [feats16: NN*1KB][out16: NN*1KB]  (if ws_size allows)
    char*  ws       = (char*)d_ws;
    int*   ej_new   = (int*)ws;
    int*   row_flag = ej_new + NN + 64;
    float* ei       = (float*)(row_flag + NN + 64);
    float* ej_orig  = ei + NN;
    size_t scal_end = (size_t)((char*)(ej_orig + NN) - ws);
    size_t f16_off  = (scal_end + 1023) & ~(size_t)1023;
    size_t f16_need = 2ull * NN * DU16 * sizeof(unsigned int);  // 102.4 MB
    const bool use16 = (ws_size >= f16_off + f16_need);
    unsigned int* feats16 = (unsigned int*)(ws + f16_off);
    unsigned int* out16   = feats16 + (size_t)NN * DU16;

    // zero ej_new + pad + row_flag
    (void)hipMemsetAsync(d_ws, 0, (size_t)(2 * NN + 128) * sizeof(int), stream);

    dim3 pb(256), pg((NN + 3) / 4);
    precomp_kernel<<<pg, pb, 0, stream>>>(feats, wq_w, wq_b, wk_w, wk_b,
                                          ei, ej_orig, use16 ? feats16 : nullptr);

    if (use16) {
        attn_dataflow_h16<<<dim3(1024), dim3(256), 0, stream>>>(
            neighbors, deg, ei, ej_orig, wk_b,
            feats16, out16, ej_new, row_flag, out);
    } else {
        attn_dataflow_f32<<<dim3(1024), dim3(256), 0, stream>>>(
            feats, neighbors, deg, ei, ej_orig, wk_w, wk_b, ej_new, out);
    }
}